// Round 11
// baseline (200.373 us; speedup 1.0000x reference)
//
#include <hip/hip_runtime.h>
#include <math.h>

#define IN_C 128
#define OUT_C 64
#define ALPHA 0.2f

#define LDK 136  // padded halfwords per LDS row (gemm)

#define BSH 7      // bucket shift: 128 nodes per bucket
#define NPB 128    // nodes per bucket
#define MAXB 1024  // max buckets (n <= 131072); dst must fit 25 bits
#define PA_EPT 16
#define PA_TILE (256 * PA_EPT)  // 4096 edges per bin block
#define CHUNK 4096  // edges LDS-sorted per pass (16 KiB of int)
#define SMEM_BYTES 41216  // max(bin: 41216, gemm: 34816)

typedef __attribute__((ext_vector_type(8))) short short8;
typedef __attribute__((ext_vector_type(4))) float v4f;

__device__ __forceinline__ ushort f2b(float f) {  // fp32 -> bf16 RNE
  unsigned u = __float_as_uint(f);
  u += 0x7fffu + ((u >> 16) & 1u);
  return (ushort)(u >> 16);
}

// ---------------------------------------------------------------------------
// fused_prep: blockIdx < nbin  -> edge binning (bucket-sorted, coalesced)
//             blockIdx >= nbin -> MFMA gemm tiles (grid-stride)
// The two phases are data-independent; fusing them time-shares the machine
// (cost ~= max instead of sum) and removes a launch boundary. LDS is aliased
// via one char array (each block runs exactly one branch).
// ---------------------------------------------------------------------------
__global__ __launch_bounds__(256) void fused_prep(
    const float* __restrict__ x, const float* __restrict__ W,
    const float* __restrict__ a, const int* __restrict__ src,
    const int* __restrict__ dst, ushort* __restrict__ hb,
    float* __restrict__ s, float* __restrict__ t, int* __restrict__ gfill,
    int* __restrict__ pairs, int nbuck, int cape, int n_nodes, int n_tiles,
    int nbin, int E) {
  __shared__ __align__(16) char smem[SMEM_BYTES];
  const int tid = threadIdx.x;

  if ((int)blockIdx.x < nbin) {
    // ---------------- binning branch ----------------
    int* hist = (int*)smem;          // 1024
    int* loffsB = hist + MAXB;       // 1024
    int* lcurB = loffsB + MAXB;      // 1024
    int* gbaseB = lcurB + MAXB;      // 1024
    int* wsumB = gbaseB + MAXB;      // 64
    int* sl = wsumB + 64;            // 4096
    ushort* sbkt = (ushort*)(sl + PA_TILE);  // 4096

    for (int i = tid; i < MAXB; i += 256) hist[i] = 0;
    __syncthreads();

    const int eblk0 = blockIdx.x * PA_TILE;
    const int nblk_edges = min(PA_TILE, E - eblk0);
    const int e0 = eblk0 + tid * PA_EPT;
    const bool full = (e0 + PA_EPT <= E);

    if (full) {
#pragma unroll
      for (int i = 0; i < PA_EPT / 4; ++i) {
        const int4 v = *(const int4*)(src + e0 + i * 4);
        atomicAdd(&hist[v.x >> BSH], 1);
        atomicAdd(&hist[v.y >> BSH], 1);
        atomicAdd(&hist[v.z >> BSH], 1);
        atomicAdd(&hist[v.w >> BSH], 1);
      }
    } else {
      for (int e = e0; e < E; ++e) atomicAdd(&hist[src[e] >> BSH], 1);
    }
    __syncthreads();

    // Block-wide exclusive scan over 1024 bucket counts (4 buckets/thread).
    const int lane = tid & 63;
    const int wid = tid >> 6;
    int c4[4], csum = 0;
#pragma unroll
    for (int j = 0; j < 4; ++j) {
      c4[j] = hist[tid * 4 + j];
      csum += c4[j];
    }
    int incl = csum;
#pragma unroll
    for (int off = 1; off < 64; off <<= 1) {
      const int o = __shfl_up(incl, off, 64);
      if (lane >= off) incl += o;
    }
    if (lane == 63) wsumB[wid] = incl;
    __syncthreads();
    if (tid == 0) {
      int r = 0;
#pragma unroll
      for (int j = 0; j < 4; ++j) {
        const int v = wsumB[j];
        wsumB[4 + j] = r;
        r += v;
      }
    }
    __syncthreads();
    int run = incl - csum + wsumB[4 + wid];
#pragma unroll
    for (int j = 0; j < 4; ++j) {
      const int bkt = tid * 4 + j;
      loffsB[bkt] = run;
      lcurB[bkt] = run;
      const int cc = c4[j];
      gbaseB[bkt] = cc ? atomicAdd(&gfill[bkt], cc) : 0;
      run += cc;
    }
    __syncthreads();

    // LDS scatter into bucket-sorted order (reload edges; L2-hot).
#define PUTS(svv, dvv)                                \
  {                                                   \
    const int bkt = (svv) >> BSH;                     \
    const int pos = atomicAdd(&lcurB[bkt], 1);        \
    sl[pos] = (((svv) & (NPB - 1)) << 25) | (dvv);    \
    sbkt[pos] = (ushort)bkt;                          \
  }
    if (full) {
#pragma unroll
      for (int i = 0; i < PA_EPT / 4; ++i) {
        const int4 sv = *(const int4*)(src + e0 + i * 4);
        const int4 dv = *(const int4*)(dst + e0 + i * 4);
        PUTS(sv.x, dv.x);
        PUTS(sv.y, dv.y);
        PUTS(sv.z, dv.z);
        PUTS(sv.w, dv.w);
      }
    } else {
      for (int e = e0; e < E; ++e) {
        const int svv = src[e];
        const int dvv = dst[e];
        PUTS(svv, dvv);
      }
    }
#undef PUTS
    __syncthreads();

    // Coalesced write-out of bucket runs.
    for (int k = tid; k < nblk_edges; k += 256) {
      const int bkt = sbkt[k];
      const int off = gbaseB[bkt] + (k - loffsB[bkt]);
      if (off < cape) pairs[bkt * cape + off] = sl[k];
    }
    return;
  }

  // ---------------- gemm branch ----------------
  ushort* xs = (ushort*)smem;      // 64*LDK
  ushort* ws = xs + 64 * LDK;      // 64*LDK

  const int wave = tid >> 6;
  const int lane = tid & 63;
  const int li = lane & 15;
  const int quad = lane >> 4;
  const int gblocks = gridDim.x - nbin;
  const int gbid = blockIdx.x - nbin;

  for (int i = tid; i < IN_C * OUT_C; i += 256) {
    const int k = i >> 6;
    const int n = i & 63;
    ws[n * LDK + k] = f2b(W[i]);
  }
  __syncthreads();

  short8 bfrag[4][4];
#pragma unroll
  for (int ct = 0; ct < 4; ++ct)
#pragma unroll
    for (int kk = 0; kk < 4; ++kk)
      bfrag[ct][kk] =
          *(const short8*)&ws[(ct * 16 + li) * LDK + kk * 32 + quad * 8];

  float a1v[4], a2v[4];
#pragma unroll
  for (int ct = 0; ct < 4; ++ct) {
    a1v[ct] = a[ct * 16 + li];
    a2v[ct] = a[OUT_C + ct * 16 + li];
  }

  for (int tile = gbid; tile < n_tiles; tile += gblocks) {
    const int row0 = tile * 64;

    __syncthreads();
    for (int i = tid; i < 64 * (IN_C / 4); i += 256) {
      const int r = i >> 5;
      const int c4 = i & 31;
      int row = row0 + r;
      row = row < n_nodes ? row : n_nodes - 1;
      const float4 v = *(const float4*)&x[(size_t)row * IN_C + c4 * 4];
      uint2 p;
      p.x = (unsigned)f2b(v.x) | ((unsigned)f2b(v.y) << 16);
      p.y = (unsigned)f2b(v.z) | ((unsigned)f2b(v.w) << 16);
      *(uint2*)&xs[r * LDK + c4 * 4] = p;
    }
    __syncthreads();

    v4f acc[4];
#pragma unroll
    for (int ct = 0; ct < 4; ++ct) acc[ct] = (v4f){0.f, 0.f, 0.f, 0.f};

    const int rbase = wave * 16;
#pragma unroll
    for (int kk = 0; kk < 4; ++kk) {
      const short8 af =
          *(const short8*)&xs[(rbase + li) * LDK + kk * 32 + quad * 8];
#pragma unroll
      for (int ct = 0; ct < 4; ++ct)
        acc[ct] = __builtin_amdgcn_mfma_f32_16x16x32_bf16(af, bfrag[ct][kk],
                                                          acc[ct], 0, 0, 0);
    }

    float ps[4] = {0.f, 0.f, 0.f, 0.f};
    float pt[4] = {0.f, 0.f, 0.f, 0.f};
#pragma unroll
    for (int ct = 0; ct < 4; ++ct) {
#pragma unroll
      for (int r = 0; r < 4; ++r) {
        const float hv = acc[ct][r];
        ps[r] += hv * a1v[ct];
        pt[r] += hv * a2v[ct];
      }
    }
#pragma unroll
    for (int m = 1; m <= 8; m <<= 1) {
#pragma unroll
      for (int r = 0; r < 4; ++r) {
        ps[r] += __shfl_xor(ps[r], m, 64);
        pt[r] += __shfl_xor(pt[r], m, 64);
      }
    }
    const int growbase = row0 + rbase + quad * 4;
    if (li < 4) {
      const int grow = growbase + li;
      if (grow < n_nodes) {
        const float sv = li == 0 ? ps[0] : li == 1 ? ps[1] : li == 2 ? ps[2] : ps[3];
        const float tv = li == 0 ? pt[0] : li == 1 ? pt[1] : li == 2 ? pt[2] : pt[3];
        s[grow] = sv;
        t[grow] = tv;
      }
    }

    // Pack acc -> LDS (row-major bf16), store hb as linear uint4.
    __syncthreads();
#pragma unroll
    for (int ct = 0; ct < 4; ++ct)
#pragma unroll
      for (int r = 0; r < 4; ++r)
        xs[(rbase + quad * 4 + r) * LDK + ct * 16 + li] = f2b(acc[ct][r]);
    __syncthreads();
    for (int j = tid; j < 64 * 8; j += 256) {
      const int row = j >> 3;
      const int u8 = j & 7;
      const int grow = row0 + row;
      if (grow < n_nodes) {
        const uint4 v = *(const uint4*)&xs[row * LDK + u8 * 8];
        *(uint4*)&hb[(size_t)grow * OUT_C + u8 * 8] = v;
      }
    }
  }
}

// ---------------------------------------------------------------------------
// aggregate_sorted: one block per bucket (128 nodes). NO fp atomics.
// (unchanged from round 8/9 -- measured ~52 us; reads gfill now)
// ---------------------------------------------------------------------------
#define ACC8(o, p, wgt)                                      \
  acc[(o) + 0] += (wgt)*__uint_as_float((p).x << 16);        \
  acc[(o) + 1] += (wgt)*__uint_as_float((p).x & 0xffff0000u);\
  acc[(o) + 2] += (wgt)*__uint_as_float((p).y << 16);        \
  acc[(o) + 3] += (wgt)*__uint_as_float((p).y & 0xffff0000u);\
  acc[(o) + 4] += (wgt)*__uint_as_float((p).z << 16);        \
  acc[(o) + 5] += (wgt)*__uint_as_float((p).z & 0xffff0000u);\
  acc[(o) + 6] += (wgt)*__uint_as_float((p).w << 16);        \
  acc[(o) + 7] += (wgt)*__uint_as_float((p).w & 0xffff0000u);

__global__ __launch_bounds__(256) void aggregate_sorted(
    const int* __restrict__ pairs, const int* __restrict__ gfill,
    const uint4* __restrict__ hb4, const float* __restrict__ s,
    const float* __restrict__ t, float* __restrict__ out, int n_nodes,
    int cape) {
  __shared__ int sl[CHUNK];
  __shared__ int cnt[NPB];
  __shared__ int loffs[NPB];
  __shared__ int cur[NPB];
  __shared__ int w0tot_sh;

  const int b = blockIdx.x;
  const int tid = threadIdx.x;
  const int base = b * cape;
  int fill = gfill[b];
  fill = fill < cape ? fill : cape;

  const int local = tid >> 1;  // node within bucket
  const int half = tid & 1;    // channel half (32 ch each)
  const int u = b * NPB + local;
  const bool valid = u < n_nodes;
  const float su = valid ? s[u] : 0.f;

  float acc[32];
#pragma unroll
  for (int i = 0; i < 32; ++i) acc[i] = 0.f;
  float den = 0.f;

  for (int c0 = 0; c0 < fill; c0 += CHUNK) {
    const int clen = min(CHUNK, fill - c0);
    if (tid < NPB) cnt[tid] = 0;
    __syncthreads();

    int pw[CHUNK / 256];
#pragma unroll
    for (int j = 0; j < CHUNK / 256; ++j) {
      const int k = j * 256 + tid;
      if (k < clen) {
        pw[j] = pairs[base + c0 + k];
        atomicAdd(&cnt[((unsigned)pw[j]) >> 25], 1);
      }
    }
    __syncthreads();

    int c = 0, incl = 0;
    if (tid < NPB) {
      c = cnt[tid];
      incl = c;
#pragma unroll
      for (int off = 1; off < 64; off <<= 1) {
        const int o = __shfl_up(incl, off, 64);
        if ((tid & 63) >= off) incl += o;
      }
      if (tid == 63) w0tot_sh = incl;
    }
    __syncthreads();
    if (tid < NPB) {
      if (tid >= 64) incl += w0tot_sh;
      loffs[tid] = incl - c;
      cur[tid] = incl - c;
    }
    __syncthreads();

#pragma unroll
    for (int j = 0; j < CHUNK / 256; ++j) {
      const int k = j * 256 + tid;
      if (k < clen) {
        const int lo = ((unsigned)pw[j]) >> 25;
        const int pos = atomicAdd(&cur[lo], 1);
        sl[pos] = pw[j] & 0x1ffffff;
      }
    }
    __syncthreads();

    const int s0 = loffs[local];
    const int s1 = s0 + cnt[local];
    int e = s0;
    for (; e + 1 < s1; e += 2) {
      const int va = sl[e];
      const int vb = sl[e + 1];
      const float ta = t[va];
      const float tb = t[vb];
      const uint4* ra = &hb4[(size_t)va * 8 + half * 4];
      const uint4* rb = &hb4[(size_t)vb * 8 + half * 4];
      const uint4 pa0 = ra[0], pa1 = ra[1], pa2 = ra[2], pa3 = ra[3];
      const uint4 pb0 = rb[0], pb1 = rb[1], pb2 = rb[2], pb3 = rb[3];
      float za = su + ta;
      float zb = su + tb;
      za = za > 0.f ? za : ALPHA * za;
      zb = zb > 0.f ? zb : ALPHA * zb;
      const float wa = __expf(za);
      const float wb = __expf(zb);
      ACC8(0, pa0, wa) ACC8(8, pa1, wa) ACC8(16, pa2, wa) ACC8(24, pa3, wa)
      ACC8(0, pb0, wb) ACC8(8, pb1, wb) ACC8(16, pb2, wb) ACC8(24, pb3, wb)
      den += wa + wb;
    }
    if (e < s1) {
      const int va = sl[e];
      const float ta = t[va];
      const uint4* ra = &hb4[(size_t)va * 8 + half * 4];
      const uint4 pa0 = ra[0], pa1 = ra[1], pa2 = ra[2], pa3 = ra[3];
      float za = su + ta;
      za = za > 0.f ? za : ALPHA * za;
      const float wa = __expf(za);
      ACC8(0, pa0, wa) ACC8(8, pa1, wa) ACC8(16, pa2, wa) ACC8(24, pa3, wa)
      den += wa;
    }
    __syncthreads();
  }

  if (valid) {
    float z0 = su + t[u];
    z0 = z0 > 0.f ? z0 : ALPHA * z0;
    const float w0 = __expf(z0);
    const uint4* rs = &hb4[(size_t)u * 8 + half * 4];
    const uint4 q0 = rs[0], q1 = rs[1], q2 = rs[2], q3 = rs[3];
    ACC8(0, q0, w0) ACC8(8, q1, w0) ACC8(16, q2, w0) ACC8(24, q3, w0)
    den += w0;
    const float inv = 1.f / den;
#pragma unroll
    for (int q = 0; q < 8; ++q) {
      float4 o;
      o.x = acc[q * 4 + 0] * inv;
      o.y = acc[q * 4 + 1] * inv;
      o.z = acc[q * 4 + 2] * inv;
      o.w = acc[q * 4 + 3] * inv;
      *(float4*)&out[(size_t)u * OUT_C + half * 32 + q * 4] = o;
    }
  }
}

extern "C" void kernel_launch(void* const* d_in, const int* in_sizes, int n_in,
                              void* d_out, int out_size, void* d_ws,
                              size_t ws_size, hipStream_t stream) {
  const float* x = (const float*)d_in[0];
  const float* W = (const float*)d_in[1];
  const float* a = (const float*)d_in[2];
  const int* edge_index = (const int*)d_in[3];

  const int n_nodes = in_sizes[0] / IN_C;
  const int E = in_sizes[3] / 2;
  const int* src = edge_index;
  const int* dst = edge_index + E;

  float* out = (float*)d_out;

  const int nbuck = (n_nodes + NPB - 1) >> BSH;
  const int cape = (((E + nbuck - 1) / nbuck) + 768 + 15) & ~15;
  const int nbin = (E + PA_TILE - 1) / PA_TILE;
  const int n_tiles = (n_nodes + 63) / 64;
  const int ngemm = n_tiles < 512 ? n_tiles : 512;

  // Workspace layout:
  ushort* hb = (ushort*)d_ws;                         // n*64 bf16 (12.8MB)
  float* s = (float*)(hb + (size_t)n_nodes * OUT_C);  // n
  float* t = s + n_nodes;                             // n
  int* gfill = (int*)(t + n_nodes);                   // MAXB
  int* pairs = gfill + MAXB;                          // nbuck*cape (~8.8MB)

  hipMemsetAsync(gfill, 0, MAXB * sizeof(int), stream);

  // Fused: binning blocks [0,nbin) || gemm blocks [nbin, nbin+ngemm)
  fused_prep<<<nbin + ngemm, 256, 0, stream>>>(x, W, a, src, dst, hb, s, t,
                                               gfill, pairs, nbuck, cape,
                                               n_nodes, n_tiles, nbin, E);

  // LDS-sort per bucket + register-accumulate + normalize + write
  aggregate_sorted<<<nbuck, 256, 0, stream>>>(pairs, gfill, (const uint4*)hb,
                                              s, t, out, n_nodes, cape);
}

// Round 12
// 170.013 us; speedup vs baseline: 1.1786x; 1.1786x over previous
//
#include <hip/hip_runtime.h>
#include <math.h>

#define IN_C 128
#define OUT_C 64
#define ALPHA 0.2f

#define LDK 136  // padded halfwords per LDS row (gemm epilogue transpose)

#define BSH 7      // bucket shift: 128 nodes per bucket
#define NPB 128    // nodes per bucket
#define MAXB 1024  // max buckets (n <= 131072); dst must fit 25 bits
#define PA_EPT 4
#define PA_THREADS 1024
#define PA_TILE (PA_THREADS * PA_EPT)  // 4096 edges per bin block
#define CHUNK 4096  // edges LDS-sorted per pass (16 KiB of int)

typedef __attribute__((ext_vector_type(8))) short short8;
typedef __attribute__((ext_vector_type(4))) float v4f;

__device__ __forceinline__ ushort f2b(float f) {  // fp32 -> bf16 RNE
  unsigned u = __float_as_uint(f);
  u += 0x7fffu + ((u >> 16) & 1u);
  return (ushort)(u >> 16);
}

// ---------------------------------------------------------------------------
// Kernel 1: h = bf16(x) @ bf16(W) via MFMA 16x16x32, fp32 accumulate.
// A-fragments are loaded DIRECTLY from global (x is L3-resident; the LDS
// input-staging round trip + 2 barriers were pure overhead). LDS (xs) is
// used only for the epilogue transpose -> linear uint4 hb stores.
// 1024-block grid (4 blocks/CU co-resident). Block 0 inits bucket cursors.
// ---------------------------------------------------------------------------
__global__ __launch_bounds__(256) void gemm_st_kernel(
    const float* __restrict__ x, const float* __restrict__ W,
    const float* __restrict__ a, ushort* __restrict__ hb,
    float* __restrict__ s, float* __restrict__ t, int* __restrict__ gcur,
    int nbuck, int cape, int n_nodes, int n_tiles) {
  __shared__ ushort xs[64 * LDK];
  __shared__ ushort ws[64 * LDK];

  const int tid = threadIdx.x;
  const int wave = tid >> 6;
  const int lane = tid & 63;
  const int li = lane & 15;
  const int quad = lane >> 4;

  if (blockIdx.x == 0) {
    for (int i = tid; i < nbuck; i += 256) gcur[i] = i * cape;
  }

  for (int i = tid; i < IN_C * OUT_C; i += 256) {
    const int k = i >> 6;
    const int n = i & 63;
    ws[n * LDK + k] = f2b(W[i]);
  }
  __syncthreads();

  short8 bfrag[4][4];
#pragma unroll
  for (int ct = 0; ct < 4; ++ct)
#pragma unroll
    for (int kk = 0; kk < 4; ++kk)
      bfrag[ct][kk] =
          *(const short8*)&ws[(ct * 16 + li) * LDK + kk * 32 + quad * 8];

  float a1v[4], a2v[4];
#pragma unroll
  for (int ct = 0; ct < 4; ++ct) {
    a1v[ct] = a[ct * 16 + li];
    a2v[ct] = a[OUT_C + ct * 16 + li];
  }

  for (int tile = blockIdx.x; tile < n_tiles; tile += gridDim.x) {
    const int row0 = tile * 64;
    const int rbase = wave * 16;

    // Direct-register A fragments: row rbase+li, cols kk*32+quad*8 .. +8.
    int arow = row0 + rbase + li;
    arow = arow < n_nodes ? arow : n_nodes - 1;
    const float* xrow = &x[(size_t)arow * IN_C];
    short8 af[4];
#pragma unroll
    for (int kk = 0; kk < 4; ++kk) {
      const float4* xp = (const float4*)&xrow[kk * 32 + quad * 8];
      const float4 v0 = xp[0];
      const float4 v1 = xp[1];
      uint4 pk;
      pk.x = (unsigned)f2b(v0.x) | ((unsigned)f2b(v0.y) << 16);
      pk.y = (unsigned)f2b(v0.z) | ((unsigned)f2b(v0.w) << 16);
      pk.z = (unsigned)f2b(v1.x) | ((unsigned)f2b(v1.y) << 16);
      pk.w = (unsigned)f2b(v1.z) | ((unsigned)f2b(v1.w) << 16);
      af[kk] = *(short8*)&pk;
    }

    v4f acc[4];
#pragma unroll
    for (int ct = 0; ct < 4; ++ct) acc[ct] = (v4f){0.f, 0.f, 0.f, 0.f};
#pragma unroll
    for (int kk = 0; kk < 4; ++kk)
#pragma unroll
      for (int ct = 0; ct < 4; ++ct)
        acc[ct] = __builtin_amdgcn_mfma_f32_16x16x32_bf16(af[kk],
                                                          bfrag[ct][kk],
                                                          acc[ct], 0, 0, 0);

    // s/t partials from acc (registers only).
    float ps[4] = {0.f, 0.f, 0.f, 0.f};
    float pt[4] = {0.f, 0.f, 0.f, 0.f};
#pragma unroll
    for (int ct = 0; ct < 4; ++ct) {
#pragma unroll
      for (int r = 0; r < 4; ++r) {
        const float hv = acc[ct][r];
        ps[r] += hv * a1v[ct];
        pt[r] += hv * a2v[ct];
      }
    }
#pragma unroll
    for (int m = 1; m <= 8; m <<= 1) {
#pragma unroll
      for (int r = 0; r < 4; ++r) {
        ps[r] += __shfl_xor(ps[r], m, 64);
        pt[r] += __shfl_xor(pt[r], m, 64);
      }
    }
    const int growbase = row0 + rbase + quad * 4;
    if (li < 4) {
      const int grow = growbase + li;
      if (grow < n_nodes) {
        const float sv = li == 0 ? ps[0] : li == 1 ? ps[1] : li == 2 ? ps[2] : ps[3];
        const float tv = li == 0 ? pt[0] : li == 1 ? pt[1] : li == 2 ? pt[2] : pt[3];
        s[grow] = sv;
        t[grow] = tv;
      }
    }

    // Epilogue: acc -> LDS (row-major bf16), store hb as linear uint4.
    __syncthreads();  // prior tile's xs reads complete
#pragma unroll
    for (int ct = 0; ct < 4; ++ct)
#pragma unroll
      for (int r = 0; r < 4; ++r)
        xs[(rbase + quad * 4 + r) * LDK + ct * 16 + li] = f2b(acc[ct][r]);
    __syncthreads();
    for (int j = tid; j < 64 * 8; j += 256) {
      const int row = j >> 3;
      const int u8 = j & 7;
      const int grow = row0 + row;
      if (grow < n_nodes) {
        const uint4 v = *(const uint4*)&xs[row * LDK + u8 * 8];
        *(uint4*)&hb[(size_t)grow * OUT_C + u8 * 8] = v;
      }
    }
  }
}

// ---------------------------------------------------------------------------
// pa_bin: edge binning by src>>BSH with LDS-SORTED coalesced output.
// (round-9 version, measured as part of the 177us best config)
// ---------------------------------------------------------------------------
__global__ __launch_bounds__(PA_THREADS) void pa_bin(
    const int* __restrict__ src, const int* __restrict__ dst,
    int* __restrict__ gcur, int* __restrict__ pairs, int nbuck, int cape,
    int E) {
  __shared__ int hist[MAXB];
  __shared__ int loffs[MAXB];
  __shared__ int lcur[MAXB];
  __shared__ int gbase[MAXB];
  __shared__ int wsum[16];
  __shared__ int sl[PA_TILE];
  __shared__ ushort sbkt[PA_TILE];

  const int tid = threadIdx.x;
  const int lane = tid & 63;
  const int wid = tid >> 6;
  hist[tid] = 0;
  __syncthreads();

  const int eblk0 = blockIdx.x * PA_TILE;
  const int nblk_edges = min(PA_TILE, E - eblk0);
  const int e0 = eblk0 + tid * PA_EPT;

  int4 sv, dv;
  const bool full = (e0 + PA_EPT <= E);
  if (full) {
    sv = *(const int4*)(src + e0);
    dv = *(const int4*)(dst + e0);
    atomicAdd(&hist[sv.x >> BSH], 1);
    atomicAdd(&hist[sv.y >> BSH], 1);
    atomicAdd(&hist[sv.z >> BSH], 1);
    atomicAdd(&hist[sv.w >> BSH], 1);
  } else {
    for (int e = e0; e < E; ++e) atomicAdd(&hist[src[e] >> BSH], 1);
  }
  __syncthreads();

  // Reserve global chunks (1 returning atomic per non-empty bucket).
  const int c = hist[tid];  // thread tid owns bucket tid (nbuck <= 1024)
  gbase[tid] = c ? atomicAdd(&gcur[tid], c) : 0;

  // Block-wide exclusive scan of bucket counts.
  int incl = c;
#pragma unroll
  for (int off = 1; off < 64; off <<= 1) {
    const int o = __shfl_up(incl, off, 64);
    if (lane >= off) incl += o;
  }
  if (lane == 63) wsum[wid] = incl;
  __syncthreads();
  if (tid < 16) {
    const int v = wsum[tid];
    int sc = v;
#pragma unroll
    for (int off = 1; off < 16; off <<= 1) {
      const int o = __shfl_up(sc, off, 64);
      if (tid >= off) sc += o;
    }
    wsum[tid] = sc - v;  // exclusive wave offset
  }
  __syncthreads();
  const int excl = incl - c + wsum[wid];
  loffs[tid] = excl;
  lcur[tid] = excl;
  __syncthreads();

  // LDS scatter into bucket-sorted order.
#define PUTS(svv, dvv)                                        \
  {                                                           \
    const int bkt = (svv) >> BSH;                             \
    const int pos = atomicAdd(&lcur[bkt], 1);                 \
    sl[pos] = (((svv) & (NPB - 1)) << 25) | (dvv);            \
    sbkt[pos] = (ushort)bkt;                                  \
  }
  if (full) {
    PUTS(sv.x, dv.x);
    PUTS(sv.y, dv.y);
    PUTS(sv.z, dv.z);
    PUTS(sv.w, dv.w);
  } else {
    for (int e = e0; e < E; ++e) {
      const int svv = src[e];
      const int dvv = dst[e];
      PUTS(svv, dvv);
    }
  }
#undef PUTS
  __syncthreads();

  // Coalesced write-out of bucket runs.
  for (int k = tid; k < nblk_edges; k += PA_THREADS) {
    const int bkt = sbkt[k];
    const int gpos = gbase[bkt] + (k - loffs[bkt]);
    if (gpos < (bkt + 1) * cape) pairs[gpos] = sl[k];
  }
}

// ---------------------------------------------------------------------------
// aggregate_sorted: one block per bucket (128 nodes). NO fp atomics.
// (round-8/9 version, measured ~52us)
// ---------------------------------------------------------------------------
#define ACC8(o, p, wgt)                                      \
  acc[(o) + 0] += (wgt)*__uint_as_float((p).x << 16);        \
  acc[(o) + 1] += (wgt)*__uint_as_float((p).x & 0xffff0000u);\
  acc[(o) + 2] += (wgt)*__uint_as_float((p).y << 16);        \
  acc[(o) + 3] += (wgt)*__uint_as_float((p).y & 0xffff0000u);\
  acc[(o) + 4] += (wgt)*__uint_as_float((p).z << 16);        \
  acc[(o) + 5] += (wgt)*__uint_as_float((p).z & 0xffff0000u);\
  acc[(o) + 6] += (wgt)*__uint_as_float((p).w << 16);        \
  acc[(o) + 7] += (wgt)*__uint_as_float((p).w & 0xffff0000u);

__global__ __launch_bounds__(256) void aggregate_sorted(
    const int* __restrict__ pairs, const int* __restrict__ gcur,
    const uint4* __restrict__ hb4, const float* __restrict__ s,
    const float* __restrict__ t, float* __restrict__ out, int n_nodes,
    int cape) {
  __shared__ int sl[CHUNK];
  __shared__ int cnt[NPB];
  __shared__ int loffs[NPB];
  __shared__ int cur[NPB];
  __shared__ int w0tot_sh;

  const int b = blockIdx.x;
  const int tid = threadIdx.x;
  const int base = b * cape;
  int fill = gcur[b] - base;
  fill = fill < cape ? fill : cape;

  const int local = tid >> 1;  // node within bucket
  const int half = tid & 1;    // channel half (32 ch each)
  const int u = b * NPB + local;
  const bool valid = u < n_nodes;
  const float su = valid ? s[u] : 0.f;

  float acc[32];
#pragma unroll
  for (int i = 0; i < 32; ++i) acc[i] = 0.f;
  float den = 0.f;

  for (int c0 = 0; c0 < fill; c0 += CHUNK) {
    const int clen = min(CHUNK, fill - c0);
    if (tid < NPB) cnt[tid] = 0;
    __syncthreads();

    int pw[CHUNK / 256];
#pragma unroll
    for (int j = 0; j < CHUNK / 256; ++j) {
      const int k = j * 256 + tid;
      if (k < clen) {
        pw[j] = pairs[base + c0 + k];
        atomicAdd(&cnt[((unsigned)pw[j]) >> 25], 1);
      }
    }
    __syncthreads();

    int c = 0, incl = 0;
    if (tid < NPB) {
      c = cnt[tid];
      incl = c;
#pragma unroll
      for (int off = 1; off < 64; off <<= 1) {
        const int o = __shfl_up(incl, off, 64);
        if ((tid & 63) >= off) incl += o;
      }
      if (tid == 63) w0tot_sh = incl;
    }
    __syncthreads();
    if (tid < NPB) {
      if (tid >= 64) incl += w0tot_sh;
      loffs[tid] = incl - c;
      cur[tid] = incl - c;
    }
    __syncthreads();

#pragma unroll
    for (int j = 0; j < CHUNK / 256; ++j) {
      const int k = j * 256 + tid;
      if (k < clen) {
        const int lo = ((unsigned)pw[j]) >> 25;
        const int pos = atomicAdd(&cur[lo], 1);
        sl[pos] = pw[j] & 0x1ffffff;
      }
    }
    __syncthreads();

    const int s0 = loffs[local];
    const int s1 = s0 + cnt[local];
    int e = s0;
    for (; e + 1 < s1; e += 2) {
      const int va = sl[e];
      const int vb = sl[e + 1];
      const float ta = t[va];
      const float tb = t[vb];
      const uint4* ra = &hb4[(size_t)va * 8 + half * 4];
      const uint4* rb = &hb4[(size_t)vb * 8 + half * 4];
      const uint4 pa0 = ra[0], pa1 = ra[1], pa2 = ra[2], pa3 = ra[3];
      const uint4 pb0 = rb[0], pb1 = rb[1], pb2 = rb[2], pb3 = rb[3];
      float za = su + ta;
      float zb = su + tb;
      za = za > 0.f ? za : ALPHA * za;
      zb = zb > 0.f ? zb : ALPHA * zb;
      const float wa = __expf(za);
      const float wb = __expf(zb);
      ACC8(0, pa0, wa) ACC8(8, pa1, wa) ACC8(16, pa2, wa) ACC8(24, pa3, wa)
      ACC8(0, pb0, wb) ACC8(8, pb1, wb) ACC8(16, pb2, wb) ACC8(24, pb3, wb)
      den += wa + wb;
    }
    if (e < s1) {
      const int va = sl[e];
      const float ta = t[va];
      const uint4* ra = &hb4[(size_t)va * 8 + half * 4];
      const uint4 pa0 = ra[0], pa1 = ra[1], pa2 = ra[2], pa3 = ra[3];
      float za = su + ta;
      za = za > 0.f ? za : ALPHA * za;
      const float wa = __expf(za);
      ACC8(0, pa0, wa) ACC8(8, pa1, wa) ACC8(16, pa2, wa) ACC8(24, pa3, wa)
      den += wa;
    }
    __syncthreads();
  }

  if (valid) {
    float z0 = su + t[u];
    z0 = z0 > 0.f ? z0 : ALPHA * z0;
    const float w0 = __expf(z0);
    const uint4* rs = &hb4[(size_t)u * 8 + half * 4];
    const uint4 q0 = rs[0], q1 = rs[1], q2 = rs[2], q3 = rs[3];
    ACC8(0, q0, w0) ACC8(8, q1, w0) ACC8(16, q2, w0) ACC8(24, q3, w0)
    den += w0;
    const float inv = 1.f / den;
#pragma unroll
    for (int q = 0; q < 8; ++q) {
      float4 o;
      o.x = acc[q * 4 + 0] * inv;
      o.y = acc[q * 4 + 1] * inv;
      o.z = acc[q * 4 + 2] * inv;
      o.w = acc[q * 4 + 3] * inv;
      *(float4*)&out[(size_t)u * OUT_C + half * 32 + q * 4] = o;
    }
  }
}

extern "C" void kernel_launch(void* const* d_in, const int* in_sizes, int n_in,
                              void* d_out, int out_size, void* d_ws,
                              size_t ws_size, hipStream_t stream) {
  const float* x = (const float*)d_in[0];
  const float* W = (const float*)d_in[1];
  const float* a = (const float*)d_in[2];
  const int* edge_index = (const int*)d_in[3];

  const int n_nodes = in_sizes[0] / IN_C;
  const int E = in_sizes[3] / 2;
  const int* src = edge_index;
  const int* dst = edge_index + E;

  float* out = (float*)d_out;

  const int nbuck = (n_nodes + NPB - 1) >> BSH;
  const int cape = (((E + nbuck - 1) / nbuck) + 768 + 15) & ~15;
  const int nblk_bin = (E + PA_TILE - 1) / PA_TILE;

  // Workspace layout:
  ushort* hb = (ushort*)d_ws;                         // n*64 bf16 (12.8MB)
  float* s = (float*)(hb + (size_t)n_nodes * OUT_C);  // n
  float* t = s + n_nodes;                             // n
  int* gcur = (int*)(t + n_nodes);                    // MAXB
  int* pairs = gcur + MAXB;                           // nbuck*cape (~8.8MB)

  // h (bf16), s, t via MFMA; block 0 also inits bucket cursors
  {
    const int n_tiles = (n_nodes + 63) / 64;
    const int ngrid = n_tiles < 1024 ? n_tiles : 1024;
    gemm_st_kernel<<<ngrid, 256, 0, stream>>>(x, W, a, hb, s, t, gcur, nbuck,
                                              cape, n_nodes, n_tiles);
  }

  // Bucket-sorted, coalesced edge binning
  pa_bin<<<nblk_bin, PA_THREADS, 0, stream>>>(src, dst, gcur, pairs, nbuck,
                                              cape, E);

  // LDS-sort per bucket + register-accumulate (w in-loop) + normalize + write
  aggregate_sorted<<<nbuck, 256, 0, stream>>>(pairs, gcur, (const uint4*)hb, s,
                                              t, out, n_nodes, cape);
}

// Round 13
// 163.702 us; speedup vs baseline: 1.2240x; 1.0385x over previous
//
#include <hip/hip_runtime.h>
#include <math.h>

#define IN_C 128
#define OUT_C 64
#define ALPHA 0.2f

#define LDK 136  // padded halfwords per LDS row (gemm epilogue transpose)

#define BSH 7      // bucket shift: 128 nodes per bucket
#define NPB 128    // nodes per bucket
#define MAXB 1024  // max buckets (n <= 131072); dst must fit 25 bits
#define PA_EPT 4
#define PA_THREADS 1024
#define PA_TILE (PA_THREADS * PA_EPT)  // 4096 edges per bin block
#define CHUNK 4096  // edges LDS-sorted per pass (16 KiB of int)
#define AGG_THREADS 512

typedef __attribute__((ext_vector_type(8))) short short8;
typedef __attribute__((ext_vector_type(4))) float v4f;

__device__ __forceinline__ ushort f2b(float f) {  // fp32 -> bf16 RNE
  unsigned u = __float_as_uint(f);
  u += 0x7fffu + ((u >> 16) & 1u);
  return (ushort)(u >> 16);
}

// ---------------------------------------------------------------------------
// Kernel 1: h = bf16(x) @ bf16(W) via MFMA 16x16x32, fp32 accumulate.
// (round-12 version: direct-register A fragments, 1024-block grid)
// ---------------------------------------------------------------------------
__global__ __launch_bounds__(256) void gemm_st_kernel(
    const float* __restrict__ x, const float* __restrict__ W,
    const float* __restrict__ a, ushort* __restrict__ hb,
    float* __restrict__ s, float* __restrict__ t, int* __restrict__ gcur,
    int nbuck, int cape, int n_nodes, int n_tiles) {
  __shared__ ushort xs[64 * LDK];
  __shared__ ushort ws[64 * LDK];

  const int tid = threadIdx.x;
  const int wave = tid >> 6;
  const int lane = tid & 63;
  const int li = lane & 15;
  const int quad = lane >> 4;

  if (blockIdx.x == 0) {
    for (int i = tid; i < nbuck; i += 256) gcur[i] = i * cape;
  }

  for (int i = tid; i < IN_C * OUT_C; i += 256) {
    const int k = i >> 6;
    const int n = i & 63;
    ws[n * LDK + k] = f2b(W[i]);
  }
  __syncthreads();

  short8 bfrag[4][4];
#pragma unroll
  for (int ct = 0; ct < 4; ++ct)
#pragma unroll
    for (int kk = 0; kk < 4; ++kk)
      bfrag[ct][kk] =
          *(const short8*)&ws[(ct * 16 + li) * LDK + kk * 32 + quad * 8];

  float a1v[4], a2v[4];
#pragma unroll
  for (int ct = 0; ct < 4; ++ct) {
    a1v[ct] = a[ct * 16 + li];
    a2v[ct] = a[OUT_C + ct * 16 + li];
  }

  for (int tile = blockIdx.x; tile < n_tiles; tile += gridDim.x) {
    const int row0 = tile * 64;
    const int rbase = wave * 16;

    // Direct-register A fragments: row rbase+li, cols kk*32+quad*8 .. +8.
    int arow = row0 + rbase + li;
    arow = arow < n_nodes ? arow : n_nodes - 1;
    const float* xrow = &x[(size_t)arow * IN_C];
    short8 af[4];
#pragma unroll
    for (int kk = 0; kk < 4; ++kk) {
      const float4* xp = (const float4*)&xrow[kk * 32 + quad * 8];
      const float4 v0 = xp[0];
      const float4 v1 = xp[1];
      uint4 pk;
      pk.x = (unsigned)f2b(v0.x) | ((unsigned)f2b(v0.y) << 16);
      pk.y = (unsigned)f2b(v0.z) | ((unsigned)f2b(v0.w) << 16);
      pk.z = (unsigned)f2b(v1.x) | ((unsigned)f2b(v1.y) << 16);
      pk.w = (unsigned)f2b(v1.z) | ((unsigned)f2b(v1.w) << 16);
      af[kk] = *(short8*)&pk;
    }

    v4f acc[4];
#pragma unroll
    for (int ct = 0; ct < 4; ++ct) acc[ct] = (v4f){0.f, 0.f, 0.f, 0.f};
#pragma unroll
    for (int kk = 0; kk < 4; ++kk)
#pragma unroll
      for (int ct = 0; ct < 4; ++ct)
        acc[ct] = __builtin_amdgcn_mfma_f32_16x16x32_bf16(af[kk],
                                                          bfrag[ct][kk],
                                                          acc[ct], 0, 0, 0);

    float ps[4] = {0.f, 0.f, 0.f, 0.f};
    float pt[4] = {0.f, 0.f, 0.f, 0.f};
#pragma unroll
    for (int ct = 0; ct < 4; ++ct) {
#pragma unroll
      for (int r = 0; r < 4; ++r) {
        const float hv = acc[ct][r];
        ps[r] += hv * a1v[ct];
        pt[r] += hv * a2v[ct];
      }
    }
#pragma unroll
    for (int m = 1; m <= 8; m <<= 1) {
#pragma unroll
      for (int r = 0; r < 4; ++r) {
        ps[r] += __shfl_xor(ps[r], m, 64);
        pt[r] += __shfl_xor(pt[r], m, 64);
      }
    }
    const int growbase = row0 + rbase + quad * 4;
    if (li < 4) {
      const int grow = growbase + li;
      if (grow < n_nodes) {
        const float sv = li == 0 ? ps[0] : li == 1 ? ps[1] : li == 2 ? ps[2] : ps[3];
        const float tv = li == 0 ? pt[0] : li == 1 ? pt[1] : li == 2 ? pt[2] : pt[3];
        s[grow] = sv;
        t[grow] = tv;
      }
    }

    // Epilogue: acc -> LDS (row-major bf16), store hb as linear uint4.
    __syncthreads();
#pragma unroll
    for (int ct = 0; ct < 4; ++ct)
#pragma unroll
      for (int r = 0; r < 4; ++r)
        xs[(rbase + quad * 4 + r) * LDK + ct * 16 + li] = f2b(acc[ct][r]);
    __syncthreads();
    for (int j = tid; j < 64 * 8; j += 256) {
      const int row = j >> 3;
      const int u8 = j & 7;
      const int grow = row0 + row;
      if (grow < n_nodes) {
        const uint4 v = *(const uint4*)&xs[row * LDK + u8 * 8];
        *(uint4*)&hb[(size_t)grow * OUT_C + u8 * 8] = v;
      }
    }
  }
}

// ---------------------------------------------------------------------------
// pa_bin: edge binning by src>>BSH with LDS-SORTED coalesced output.
// (round-9/12 version, unchanged)
// ---------------------------------------------------------------------------
__global__ __launch_bounds__(PA_THREADS) void pa_bin(
    const int* __restrict__ src, const int* __restrict__ dst,
    int* __restrict__ gcur, int* __restrict__ pairs, int nbuck, int cape,
    int E) {
  __shared__ int hist[MAXB];
  __shared__ int loffs[MAXB];
  __shared__ int lcur[MAXB];
  __shared__ int gbase[MAXB];
  __shared__ int wsum[16];
  __shared__ int sl[PA_TILE];
  __shared__ ushort sbkt[PA_TILE];

  const int tid = threadIdx.x;
  const int lane = tid & 63;
  const int wid = tid >> 6;
  hist[tid] = 0;
  __syncthreads();

  const int eblk0 = blockIdx.x * PA_TILE;
  const int nblk_edges = min(PA_TILE, E - eblk0);
  const int e0 = eblk0 + tid * PA_EPT;

  int4 sv, dv;
  const bool full = (e0 + PA_EPT <= E);
  if (full) {
    sv = *(const int4*)(src + e0);
    dv = *(const int4*)(dst + e0);
    atomicAdd(&hist[sv.x >> BSH], 1);
    atomicAdd(&hist[sv.y >> BSH], 1);
    atomicAdd(&hist[sv.z >> BSH], 1);
    atomicAdd(&hist[sv.w >> BSH], 1);
  } else {
    for (int e = e0; e < E; ++e) atomicAdd(&hist[src[e] >> BSH], 1);
  }
  __syncthreads();

  const int c = hist[tid];
  gbase[tid] = c ? atomicAdd(&gcur[tid], c) : 0;

  int incl = c;
#pragma unroll
  for (int off = 1; off < 64; off <<= 1) {
    const int o = __shfl_up(incl, off, 64);
    if (lane >= off) incl += o;
  }
  if (lane == 63) wsum[wid] = incl;
  __syncthreads();
  if (tid < 16) {
    const int v = wsum[tid];
    int sc = v;
#pragma unroll
    for (int off = 1; off < 16; off <<= 1) {
      const int o = __shfl_up(sc, off, 64);
      if (tid >= off) sc += o;
    }
    wsum[tid] = sc - v;
  }
  __syncthreads();
  const int excl = incl - c + wsum[wid];
  loffs[tid] = excl;
  lcur[tid] = excl;
  __syncthreads();

#define PUTS(svv, dvv)                                        \
  {                                                           \
    const int bkt = (svv) >> BSH;                             \
    const int pos = atomicAdd(&lcur[bkt], 1);                 \
    sl[pos] = (((svv) & (NPB - 1)) << 25) | (dvv);            \
    sbkt[pos] = (ushort)bkt;                                  \
  }
  if (full) {
    PUTS(sv.x, dv.x);
    PUTS(sv.y, dv.y);
    PUTS(sv.z, dv.z);
    PUTS(sv.w, dv.w);
  } else {
    for (int e = e0; e < E; ++e) {
      const int svv = src[e];
      const int dvv = dst[e];
      PUTS(svv, dvv);
    }
  }
#undef PUTS
  __syncthreads();

  for (int k = tid; k < nblk_edges; k += PA_THREADS) {
    const int bkt = sbkt[k];
    const int gpos = gbase[bkt] + (k - loffs[bkt]);
    if (gpos < (bkt + 1) * cape) pairs[gpos] = sl[k];
  }
}

// ---------------------------------------------------------------------------
// aggregate_sorted: one 512-THREAD block per bucket (128 nodes).
// 8 waves/block (was 4) -> 24 waves/CU potential (grid was the occupancy
// cap at 782 blocks x 4 waves = 3 waves/SIMD). 4 threads/node, 16 ch each
// (2 x uint4 per edge), acc[16]. Sort machinery unchanged, executed by 2x
// threads. NO fp atomics.
// ---------------------------------------------------------------------------
#define ACC8(o, p, wgt)                                      \
  acc[(o) + 0] += (wgt)*__uint_as_float((p).x << 16);        \
  acc[(o) + 1] += (wgt)*__uint_as_float((p).x & 0xffff0000u);\
  acc[(o) + 2] += (wgt)*__uint_as_float((p).y << 16);        \
  acc[(o) + 3] += (wgt)*__uint_as_float((p).y & 0xffff0000u);\
  acc[(o) + 4] += (wgt)*__uint_as_float((p).z << 16);        \
  acc[(o) + 5] += (wgt)*__uint_as_float((p).z & 0xffff0000u);\
  acc[(o) + 6] += (wgt)*__uint_as_float((p).w << 16);        \
  acc[(o) + 7] += (wgt)*__uint_as_float((p).w & 0xffff0000u);

__global__ __launch_bounds__(AGG_THREADS) void aggregate_sorted(
    const int* __restrict__ pairs, const int* __restrict__ gcur,
    const uint4* __restrict__ hb4, const float* __restrict__ s,
    const float* __restrict__ t, float* __restrict__ out, int n_nodes,
    int cape) {
  __shared__ int sl[CHUNK];
  __shared__ int cnt[NPB];
  __shared__ int loffs[NPB];
  __shared__ int cur[NPB];
  __shared__ int w0tot_sh;

  const int b = blockIdx.x;
  const int tid = threadIdx.x;
  const int base = b * cape;
  int fill = gcur[b] - base;
  fill = fill < cape ? fill : cape;

  const int local = tid >> 2;   // node within bucket (0..127)
  const int quarter = tid & 3;  // channel quarter (16 ch each)
  const int u = b * NPB + local;
  const bool valid = u < n_nodes;
  const float su = valid ? s[u] : 0.f;

  float acc[16];
#pragma unroll
  for (int i = 0; i < 16; ++i) acc[i] = 0.f;
  float den = 0.f;

  for (int c0 = 0; c0 < fill; c0 += CHUNK) {
    const int clen = min(CHUNK, fill - c0);
    if (tid < NPB) cnt[tid] = 0;
    __syncthreads();

    // Load this chunk's packed pairs into registers + histogram locals.
    int pw[CHUNK / AGG_THREADS];
#pragma unroll
    for (int j = 0; j < CHUNK / AGG_THREADS; ++j) {
      const int k = j * AGG_THREADS + tid;
      if (k < clen) {
        pw[j] = pairs[base + c0 + k];
        atomicAdd(&cnt[((unsigned)pw[j]) >> 25], 1);
      }
    }
    __syncthreads();

    // Exclusive scan over cnt[128] via two wave-level shfl scans.
    int c = 0, incl = 0;
    if (tid < NPB) {
      c = cnt[tid];
      incl = c;
#pragma unroll
      for (int off = 1; off < 64; off <<= 1) {
        const int o = __shfl_up(incl, off, 64);
        if ((tid & 63) >= off) incl += o;
      }
      if (tid == 63) w0tot_sh = incl;
    }
    __syncthreads();
    if (tid < NPB) {
      if (tid >= 64) incl += w0tot_sh;
      loffs[tid] = incl - c;
      cur[tid] = incl - c;
    }
    __syncthreads();

    // Scatter dst into LDS-sorted list via int cursor atomics.
#pragma unroll
    for (int j = 0; j < CHUNK / AGG_THREADS; ++j) {
      const int k = j * AGG_THREADS + tid;
      if (k < clen) {
        const int lo = ((unsigned)pw[j]) >> 25;
        const int pos = atomicAdd(&cur[lo], 1);
        sl[pos] = pw[j] & 0x1ffffff;
      }
    }
    __syncthreads();

    // Node-parallel register accumulation: 4 threads/node, 16 ch each.
    const int s0 = loffs[local];
    const int s1 = s0 + cnt[local];
    int e = s0;
    for (; e + 1 < s1; e += 2) {
      const int va = sl[e];
      const int vb = sl[e + 1];
      const float ta = t[va];
      const float tb = t[vb];
      const uint4* ra = &hb4[(size_t)va * 8 + quarter * 2];
      const uint4* rb = &hb4[(size_t)vb * 8 + quarter * 2];
      const uint4 pa0 = ra[0], pa1 = ra[1];
      const uint4 pb0 = rb[0], pb1 = rb[1];
      float za = su + ta;
      float zb = su + tb;
      za = za > 0.f ? za : ALPHA * za;
      zb = zb > 0.f ? zb : ALPHA * zb;
      const float wa = __expf(za);
      const float wb = __expf(zb);
      ACC8(0, pa0, wa) ACC8(8, pa1, wa)
      ACC8(0, pb0, wb) ACC8(8, pb1, wb)
      den += wa + wb;
    }
    if (e < s1) {
      const int va = sl[e];
      const float ta = t[va];
      const uint4* ra = &hb4[(size_t)va * 8 + quarter * 2];
      const uint4 pa0 = ra[0], pa1 = ra[1];
      float za = su + ta;
      za = za > 0.f ? za : ALPHA * za;
      const float wa = __expf(za);
      ACC8(0, pa0, wa) ACC8(8, pa1, wa)
      den += wa;
    }
    __syncthreads();
  }

  // Self-loop + normalize + write (16 channels per thread).
  if (valid) {
    float z0 = su + t[u];
    z0 = z0 > 0.f ? z0 : ALPHA * z0;
    const float w0 = __expf(z0);
    const uint4* rs = &hb4[(size_t)u * 8 + quarter * 2];
    const uint4 q0 = rs[0], q1 = rs[1];
    ACC8(0, q0, w0) ACC8(8, q1, w0)
    den += w0;
    const float inv = 1.f / den;
#pragma unroll
    for (int q = 0; q < 4; ++q) {
      float4 o;
      o.x = acc[q * 4 + 0] * inv;
      o.y = acc[q * 4 + 1] * inv;
      o.z = acc[q * 4 + 2] * inv;
      o.w = acc[q * 4 + 3] * inv;
      *(float4*)&out[(size_t)u * OUT_C + quarter * 16 + q * 4] = o;
    }
  }
}

extern "C" void kernel_launch(void* const* d_in, const int* in_sizes, int n_in,
                              void* d_out, int out_size, void* d_ws,
                              size_t ws_size, hipStream_t stream) {
  const float* x = (const float*)d_in[0];
  const float* W = (const float*)d_in[1];
  const float* a = (const float*)d_in[2];
  const int* edge_index = (const int*)d_in[3];

  const int n_nodes = in_sizes[0] / IN_C;
  const int E = in_sizes[3] / 2;
  const int* src = edge_index;
  const int* dst = edge_index + E;

  float* out = (float*)d_out;

  const int nbuck = (n_nodes + NPB - 1) >> BSH;
  const int cape = (((E + nbuck - 1) / nbuck) + 768 + 15) & ~15;
  const int nblk_bin = (E + PA_TILE - 1) / PA_TILE;

  // Workspace layout:
  ushort* hb = (ushort*)d_ws;                         // n*64 bf16 (12.8MB)
  float* s = (float*)(hb + (size_t)n_nodes * OUT_C);  // n
  float* t = s + n_nodes;                             // n
  int* gcur = (int*)(t + n_nodes);                    // MAXB
  int* pairs = gcur + MAXB;                           // nbuck*cape (~8.8MB)

  // h (bf16), s, t via MFMA; block 0 also inits bucket cursors
  {
    const int n_tiles = (n_nodes + 63) / 64;
    const int ngrid = n_tiles < 1024 ? n_tiles : 1024;
    gemm_st_kernel<<<ngrid, 256, 0, stream>>>(x, W, a, hb, s, t, gcur, nbuck,
                                              cape, n_nodes, n_tiles);
  }

  // Bucket-sorted, coalesced edge binning
  pa_bin<<<nblk_bin, PA_THREADS, 0, stream>>>(src, dst, gcur, pairs, nbuck,
                                              cape, E);

  // LDS-sort per bucket + register-accumulate (512 threads) + write
  aggregate_sorted<<<nbuck, AGG_THREADS, 0, stream>>>(
      pairs, gcur, (const uint4*)hb, s, t, out, n_nodes, cape);
}